// Round 10
// baseline (343.256 us; speedup 1.0000x reference)
//
#include <hip/hip_runtime.h>

typedef _Float16 f16;
typedef f16  f16x8  __attribute__((ext_vector_type(8)));
typedef f16  f16x4v __attribute__((ext_vector_type(4)));
typedef float f32x4 __attribute__((ext_vector_type(4)));

#define MFMA_F16(a,b,c) __builtin_amdgcn_mfma_f32_16x16x32_f16((a),(b),(c),0,0,0)

#define NWIN 512
// R10: k-tilde restructure. logit_h(q,k) = Qn_full[q] . k~_h[k], where
// k~_h[d] = pcw[h][head(d)]*K1n[k][d] + pcw[h][8+head(d)]*K2n[k][d].
// Head blocks (32 dims) == MFMA K=32 chunks -> logits via K=256 MFMA chain.
// Eliminates: Sb score buffer, fdot2 channel mix, B1/B2 barriers.
// Shape: grid 256, 1024 threads (16 waves), 160KB LDS, 2 windows/block.
// LDS regions (32768 B each, all [rows][512B or 128B] XOR-swizzled via
// byte ^= (row&7)<<4 on BOTH write and read — same involution, bijective
// per row window by construction):
#define RA 0        // bufX1 -> Q1n -> preB (both views)
#define RB 32768    // bufX2 -> Q2n
#define RC 65536    // V1 scratch -> K1n
#define RD 98304    // V2 scratch -> K2n
#define RE 131072   // P transpose tiles: 16 waves x 2048 B (wave-private)
#define SM_BYTES 163840

__device__ __forceinline__ int swz512(int row, int colByte) {
  return row * 512 + (colByte ^ ((row & 7) << 4));
}
__device__ __forceinline__ int swz128(int row, int colByte) {
  return row * 128 + (colByte ^ ((row & 7) << 4));
}

// load 8 consecutive fp32, round to f16x8
__device__ __forceinline__ f16x8 ld_f16x8(const float* __restrict__ p) {
  f32x4 a = *(const f32x4*)p;
  f32x4 b = *(const f32x4*)(p + 4);
  f16x8 r;
  r[0] = (f16)a[0]; r[1] = (f16)a[1]; r[2] = (f16)a[2]; r[3] = (f16)a[3];
  r[4] = (f16)b[0]; r[5] = (f16)b[1]; r[6] = (f16)b[2]; r[7] = (f16)b[3];
  return r;
}

// ---------------- prep: CPB MLP table + weight f32->f16 conversion ----------
// cpb output layout: tblT[view][h][226] f32 (head-major: per-wave gathers hit
// a contiguous 226-entry run; read from global via L1 in fused_attn).
__global__ __launch_bounds__(256) void prep_all(
    const float* __restrict__ w1a, const float* __restrict__ b1a,
    const float* __restrict__ w2a,
    const float* __restrict__ w1b, const float* __restrict__ b1b,
    const float* __restrict__ w2b,
    const float* __restrict__ qkvw1, const float* __restrict__ qkvw2,
    const float* __restrict__ pw1, const float* __restrict__ pw2,
    float* __restrict__ tblT,
    f16* __restrict__ wq1f, f16* __restrict__ wq2f,
    f16* __restrict__ pw1f, f16* __restrict__ pw2f) {
  const int b = blockIdx.x;
  if (b >= 450) {
    const int cb = b - 450;
    const float* src; f16* dst; int base;
    if (cb < 96)       { src = qkvw1; dst = wq1f; base = cb * 2048; }
    else if (cb < 192) { src = qkvw2; dst = wq2f; base = (cb - 96) * 2048; }
    else if (cb < 224) { src = pw1;   dst = pw1f; base = (cb - 192) * 2048; }
    else               { src = pw2;   dst = pw2f; base = (cb - 224) * 2048; }
    const int o = base + threadIdx.x * 8;
    *(f16x8*)(dst + o) = ld_f16x8(src + o);
    return;
  }
  const int view = b / 225;
  const int e    = b % 225;
  const float* __restrict__ w1 = view ? w1b : w1a;
  const float* __restrict__ b1 = view ? b1b : b1a;
  const float* __restrict__ w2 = view ? w2b : w2a;
  const int t = threadIdx.x;
  const int i = e / 15, j = e % 15;
  const float vi = 8.0f * (float)(i - 7) * (1.0f / 7.0f);
  const float vj = 8.0f * (float)(j - 7) * (1.0f / 7.0f);
  const float in0 = copysignf(log2f(fabsf(vi) + 1.0f) * (1.0f / 3.0f), vi);
  const float in1 = copysignf(log2f(fabsf(vj) + 1.0f) * (1.0f / 3.0f), vj);
  float acc[8] = {0.f,0.f,0.f,0.f,0.f,0.f,0.f,0.f};
#pragma unroll
  for (int uu = 0; uu < 2; ++uu) {
    const int u = t + uu * 256;
    float hv = fmaxf(w1[2*u] * in0 + w1[2*u+1] * in1 + b1[u], 0.0f);
#pragma unroll
    for (int hh = 0; hh < 8; ++hh) acc[hh] += w2[hh*512 + u] * hv;
  }
#pragma unroll
  for (int off = 32; off >= 1; off >>= 1)
#pragma unroll
    for (int hh = 0; hh < 8; ++hh) acc[hh] += __shfl_xor(acc[hh], off, 64);
  __shared__ float red[4][8];
  if ((t & 63) == 0) {
#pragma unroll
    for (int hh = 0; hh < 8; ++hh) red[t >> 6][hh] = acc[hh];
  }
  __syncthreads();
  if (t < 8) {
    float s = red[0][t] + red[1][t] + red[2][t] + red[3][t];
    tblT[(view * 8 + t) * 226 + e] = 16.0f / (1.0f + __expf(-s));
  }
}

// ---------------- fused: 2 windows/block, view-parallel QKV, k~ attention ----
__global__ __launch_bounds__(1024, 4) void fused_attn(
    const float* __restrict__ x1, const float* __restrict__ x2,
    const f16* __restrict__ qkvw1, const float* __restrict__ qb1, const float* __restrict__ vb1,
    const f16* __restrict__ qkvw2, const float* __restrict__ qb2, const float* __restrict__ vb2,
    const float* __restrict__ pcw1, const float* __restrict__ pcb1, const float* __restrict__ ls1,
    const float* __restrict__ pcw2, const float* __restrict__ pcb2, const float* __restrict__ ls2,
    const f16* __restrict__ pw1, const float* __restrict__ pb1,
    const f16* __restrict__ pw2, const float* __restrict__ pb2,
    const float* __restrict__ tblT,
    float* __restrict__ outp) {
  const int tid = threadIdx.x;
  const int lane = tid & 63;
  const int w = tid >> 6;            // wave 0..15
  const int quad = lane >> 4, m = lane & 15;
  const int vgrp = w >> 3;           // QKV view group / attention q-half s
  const int h = w & 7;               // head

  __shared__ __align__(16) char sm[SM_BYTES];
  const f32x4 z4 = {0.f, 0.f, 0.f, 0.f};

  f16x8 bvF[2][2][2];                // V fragments, both views, own head

  char* bufX = sm + (vgrp ? RB : RA);
  char* Karr = sm + (vgrp ? RD : RC);  // V scratch first, then K array
  const f16* W = vgrp ? qkvw2 : qkvw1;
  const float* qb = vgrp ? qb2 : qb1;
  const float* vb = vgrp ? vb2 : vb1;

  for (int wi = 0; wi < 2; ++wi) {
    const int win = blockIdx.x * 2 + wi;

    // ---- stage x1 AND x2 (all 1024 threads) ----
    for (int i = tid; i < 4096; i += 1024) {
      const int vv = i >> 11, row = (i >> 5) & 63, c8 = i & 31;
      const float* src = (vv ? x2 : x1) + (size_t)win * (64 * 256) + row * 256 + c8 * 8;
      *(f16x8*)(sm + (vv ? RB : RA) + swz512(row, c8 * 16)) = ld_f16x8(src);
    }
    __syncthreads();   // bufX1/bufX2 ready

    // ---- QKV (view-parallel: group vgrp computes its view's V,K,Q) ----
    for (int si = 0; si < 3; ++si) {
      const int sec = 2 - si;          // order: V(2), K(1), Q(0)
      f32x4 acc0[4], acc1[4];
#pragma unroll
      for (int t = 0; t < 4; ++t) { acc0[t] = z4; acc1[t] = z4; }
      const f16* wb = W + (size_t)(sec * 256 + h * 32) * 256 + quad * 8;
      __builtin_amdgcn_s_setprio(1);
#pragma unroll 2
      for (int k8 = 0; k8 < 8; ++k8) {
        f16x8 a0 = *(const f16x8*)(wb + (size_t)m * 256 + k8 * 32);
        f16x8 a1 = *(const f16x8*)(wb + (size_t)(16 + m) * 256 + k8 * 32);
#pragma unroll
        for (int tt = 0; tt < 4; ++tt) {
          f16x8 bfr = *(const f16x8*)(bufX + swz512(tt * 16 + m, k8 * 64 + quad * 16));
          acc0[tt] = MFMA_F16(a0, bfr, acc0[tt]);
          acc1[tt] = MFMA_F16(a1, bfr, acc1[tt]);
        }
      }
      __builtin_amdgcn_s_setprio(0);
      if (sec == 0) __syncthreads();   // all bufX reads done before Q overwrites it

      float bs0[4], bs1[4];
#pragma unroll
      for (int r = 0; r < 4; ++r) {
        int c0 = h * 32 + quad * 4 + r;
        bs0[r] = (sec == 0) ? qb[c0] : (sec == 2 ? vb[c0] : 0.f);
        bs1[r] = (sec == 0) ? qb[c0 + 16] : (sec == 2 ? vb[c0 + 16] : 0.f);
      }
#pragma unroll
      for (int tt = 0; tt < 4; ++tt) {
        float v0[4], v1[4];
#pragma unroll
        for (int r = 0; r < 4; ++r) { v0[r] = acc0[tt][r] + bs0[r]; v1[r] = acc1[tt][r] + bs1[r]; }
        if (sec < 2) {               // l2norm for Q and K (per head, 32 dims)
          float ss = 0.f;
#pragma unroll
          for (int r = 0; r < 4; ++r) ss += v0[r] * v0[r] + v1[r] * v1[r];
          ss += __shfl_xor(ss, 16, 64);
          ss += __shfl_xor(ss, 32, 64);
          float sc = 1.0f / fmaxf(sqrtf(ss), 1e-12f);
#pragma unroll
          for (int r = 0; r < 4; ++r) { v0[r] *= sc; v1[r] *= sc; }
        }
        const int n = tt * 16 + m;
        if (sec < 2) {
          // Q -> own bufX region; K -> Karr. Layout [64 tok][256 d] swz512.
          char* dst = (sec == 0) ? bufX : Karr;
          f16x4v p0, p1;
#pragma unroll
          for (int r = 0; r < 4; ++r) { p0[r] = (f16)v0[r]; p1[r] = (f16)v1[r]; }
          *(f16x4v*)(dst + swz512(n, h * 64 + quad * 8))      = p0;
          *(f16x4v*)(dst + swz512(n, h * 64 + 32 + quad * 8)) = p1;
        } else {
          // V scratch: per-head [32 ch][64 tok] swz128 at Karr + h*4096
#pragma unroll
          for (int r = 0; r < 4; ++r) {
            *(f16*)(Karr + h * 4096 + swz128(quad * 4 + r, n * 2))      = (f16)v0[r];
            *(f16*)(Karr + h * 4096 + swz128(16 + quad * 4 + r, n * 2)) = (f16)v1[r];
          }
        }
      }
      if (sec == 2) {
        __syncthreads();             // both groups' V scratch complete
        // every wave loads BOTH views' V fragments for its head
#pragma unroll
        for (int vv = 0; vv < 2; ++vv) {
          char* vs = sm + (vv ? RD : RC) + h * 4096;
#pragma unroll
          for (int nt = 0; nt < 2; ++nt)
#pragma unroll
            for (int kv = 0; kv < 2; ++kv)
              bvF[vv][nt][kv] = *(const f16x8*)(vs + swz128(nt * 16 + m, kv * 64 + quad * 16));
        }
        __syncthreads();             // V reads done; K may overwrite scratch
      }
    }
    __syncthreads();                 // Q1,Q2,K1,K2 arrays ready

    // ================= attention + proj, both views =================
    for (int vv = 0; vv < 2; ++vv) {
      const float* pcw = vv ? pcw2 : pcw1;
      f16 ws[8], wd[8];
#pragma unroll
      for (int c = 0; c < 8; ++c) {
        ws[c] = (f16)pcw[h * 16 + c];
        wd[c] = (f16)pcw[h * 16 + 8 + c];
      }
      const float pcb_h = (vv ? pcb2 : pcb1)[h];
      const float lsv = (vv ? ls2 : ls1)[h];
      const float scale_h = __expf(fminf(lsv, 4.6051702f));
      const float pcbs = pcb_h * scale_h;
      const float* tb = tblT + (vv * 8 + h) * 226;
      char* Q  = sm + (vv ? RB : RA);
      char* Ks = sm + (vv ? RD : RC);
      char* Kd = sm + (vv ? RC : RD);

      // ---- logits: acc[qtl][kt] = Qn_full . k~_h, K=256 via 8 chunks ----
      f32x4 acc[2][4];
#pragma unroll
      for (int a = 0; a < 2; ++a)
#pragma unroll
        for (int b = 0; b < 4; ++b) acc[a][b] = z4;
      __builtin_amdgcn_s_setprio(1);
#pragma unroll
      for (int c = 0; c < 8; ++c) {
        f16x8 qa0 = *(const f16x8*)(Q + swz512(vgrp * 32 + m,      c * 64 + quad * 16));
        f16x8 qa1 = *(const f16x8*)(Q + swz512(vgrp * 32 + 16 + m, c * 64 + quad * 16));
        const f16 wsc = ws[c], wdc = wd[c];
#pragma unroll
        for (int kt = 0; kt < 4; ++kt) {
          f16x8 k1 = *(const f16x8*)(Ks + swz512(kt * 16 + m, c * 64 + quad * 16));
          f16x8 k2 = *(const f16x8*)(Kd + swz512(kt * 16 + m, c * 64 + quad * 16));
          f16x8 kk;
#pragma unroll
          for (int j = 0; j < 8; ++j) kk[j] = (f16)(k1[j] * wsc + k2[j] * wdc);
          acc[0][kt] = MFMA_F16(qa0, kk, acc[0][kt]);
          acc[1][kt] = MFMA_F16(qa1, kk, acc[1][kt]);
        }
      }
      __builtin_amdgcn_s_setprio(0);

      // ---- per q-tile: bias, softmax (C-layout), P transpose, AV ----
      f32x4 oacc[2][2];
      char* Pt = sm + RE + w * 2048;   // wave-private [16 q][64 k] f16
#pragma unroll
      for (int qtl = 0; qtl < 2; ++qtl) {
        float logit[4][4];             // [kt][r]
#pragma unroll
        for (int kt = 0; kt < 4; ++kt) {
          const int k0 = kt * 16 + m;
          const int kh = k0 >> 3, kw = k0 & 7;
#pragma unroll
          for (int r = 0; r < 4; ++r) {
            const int q = (vgrp * 2 + qtl) * 16 + quad * 4 + r;
            const int idx = ((q >> 3) - kh + 7) * 15 + ((q & 7) - kw + 7);
            logit[kt][r] = acc[qtl][kt][r] * scale_h + pcbs + tb[idx];
          }
        }
#pragma unroll
        for (int r = 0; r < 4; ++r) {
          float mr = fmaxf(fmaxf(logit[0][r], logit[1][r]),
                           fmaxf(logit[2][r], logit[3][r]));
          mr = fmaxf(mr, __shfl_xor(mr, 1, 64));
          mr = fmaxf(mr, __shfl_xor(mr, 2, 64));
          mr = fmaxf(mr, __shfl_xor(mr, 4, 64));
          mr = fmaxf(mr, __shfl_xor(mr, 8, 64));
          float p0 = __expf(logit[0][r] - mr), p1 = __expf(logit[1][r] - mr);
          float p2 = __expf(logit[2][r] - mr), p3 = __expf(logit[3][r] - mr);
          float sr = p0 + p1 + p2 + p3;
          sr += __shfl_xor(sr, 1, 64);
          sr += __shfl_xor(sr, 2, 64);
          sr += __shfl_xor(sr, 4, 64);
          sr += __shfl_xor(sr, 8, 64);
          const float inv = 1.0f / sr;
          logit[0][r] = p0 * inv; logit[1][r] = p1 * inv;
          logit[2][r] = p2 * inv; logit[3][r] = p3 * inv;
        }
        // P tile write (C-layout) then read back as AV A-operand (same wave,
        // no barrier; 16-way read conflict accepted — 2 reads only)
#pragma unroll
        for (int kt = 0; kt < 4; ++kt)
#pragma unroll
          for (int r = 0; r < 4; ++r)
            *(f16*)(Pt + (quad * 4 + r) * 128 + (kt * 16 + m) * 2) = (f16)logit[kt][r];
        f16x8 av0 = *(const f16x8*)(Pt + m * 128 + quad * 16);
        f16x8 av1 = *(const f16x8*)(Pt + m * 128 + 64 + quad * 16);
#pragma unroll
        for (int nt = 0; nt < 2; ++nt) {
          f32x4 z = z4;
          z = MFMA_F16(av0, bvF[vv][nt][0], z);
          z = MFMA_F16(av1, bvF[vv][nt][1], z);
          oacc[qtl][nt] = z;
        }
      }

      // ---- preB (region RA) + proj ----
      __syncthreads();   // all Q/preB-region reads done before overwrite
      char* preB = sm + RA;
#pragma unroll
      for (int qtl = 0; qtl < 2; ++qtl)
#pragma unroll
        for (int nt = 0; nt < 2; ++nt)
#pragma unroll
          for (int r = 0; r < 4; ++r) {
            const int row = vgrp * 32 + qtl * 16 + quad * 4 + r;
            *(f16*)(preB + swz512(row, (h * 32 + nt * 16 + m) * 2)) = (f16)oacc[qtl][nt][r];
          }
      __syncthreads();   // preB ready
      const f16* Wp = vv ? pw2 : pw1;
      const float* pb = vv ? pb2 : pb1;
      f32x4 pacc[4];
#pragma unroll
      for (int t = 0; t < 4; ++t) pacc[t] = z4;
      __builtin_amdgcn_s_setprio(1);
#pragma unroll 2
      for (int ks = 0; ks < 8; ++ks) {
        f16x8 pa = *(const f16x8*)(Wp + (size_t)(w * 16 + m) * 256 + ks * 32 + quad * 8);
#pragma unroll
        for (int tt = 0; tt < 4; ++tt) {
          f16x8 bfr = *(const f16x8*)(preB + swz512(tt * 16 + m, ks * 64 + quad * 16));
          pacc[tt] = MFMA_F16(pa, bfr, pacc[tt]);
        }
      }
      __builtin_amdgcn_s_setprio(0);
      float* obase = outp + (size_t)(vv * NWIN + win) * (64 * 256);
#pragma unroll
      for (int tt = 0; tt < 4; ++tt) {
        f32x4 p0;
#pragma unroll
        for (int r = 0; r < 4; ++r) p0[r] = pacc[tt][r] + pb[w * 16 + quad * 4 + r];
        *(f32x4*)(obase + (tt * 16 + m) * 256 + w * 16 + quad * 4) = p0;
      }
    }
    __syncthreads();   // window done; RA/RB reused for next window's staging
  }
}

extern "C" void kernel_launch(void* const* d_in, const int* in_sizes, int n_in,
                              void* d_out, int out_size, void* d_ws, size_t ws_size,
                              hipStream_t stream) {
  (void)in_sizes; (void)n_in; (void)out_size; (void)ws_size;
  const float* x1   = (const float*)d_in[0];
  const float* x2   = (const float*)d_in[1];
  const float* qkvw1= (const float*)d_in[2];
  const float* qb1  = (const float*)d_in[3];
  const float* vb1  = (const float*)d_in[4];
  const float* pw1  = (const float*)d_in[5];
  const float* pb1  = (const float*)d_in[6];
  const float* ls1  = (const float*)d_in[7];
  const float* cw11 = (const float*)d_in[8];
  const float* cb11 = (const float*)d_in[9];
  const float* cw12 = (const float*)d_in[10];
  const float* pcw1 = (const float*)d_in[11];
  const float* pcb1 = (const float*)d_in[12];
  const float* qkvw2= (const float*)d_in[13];
  const float* qb2  = (const float*)d_in[14];
  const float* vb2  = (const float*)d_in[15];
  const float* pw2  = (const float*)d_in[16];
  const float* pb2  = (const float*)d_in[17];
  const float* ls2  = (const float*)d_in[18];
  const float* cw21 = (const float*)d_in[19];
  const float* cb21 = (const float*)d_in[20];
  const float* cw22 = (const float*)d_in[21];
  const float* pcw2 = (const float*)d_in[22];
  const float* pcb2 = (const float*)d_in[23];

  // workspace: tblT [2][8][226] f32 (14464 B) | qkvw1 f16 | qkvw2 f16 |
  // pw1 f16 | pw2 f16  -> ~1.04 MB
  float* TBLT = (float*)d_ws;
  f16* wq1f = (f16*)((char*)d_ws + 14464);
  f16* wq2f = wq1f + 196608;
  f16* pw1f = wq2f + 196608;
  f16* pw2f = pw1f + 65536;
  float* out = (float*)d_out;

  prep_all<<<706, 256, 0, stream>>>(cw11, cb11, cw12, cw21, cb21, cw22,
                                    qkvw1, qkvw2, pw1, pw2,
                                    TBLT, wq1f, wq2f, pw1f, pw2f);
  fused_attn<<<256, 1024, 0, stream>>>(x1, x2,
      wq1f, qb1, vb1, wq2f, qb2, vb2,
      pcw1, pcb1, ls1, pcw2, pcb2, ls2,
      pw1f, pb1, pw2f, pb2, TBLT, out);
}

// Round 11
// 274.060 us; speedup vs baseline: 1.2525x; 1.2525x over previous
//
#include <hip/hip_runtime.h>

typedef _Float16 f16;
typedef f16  f16x8  __attribute__((ext_vector_type(8)));
typedef f16  f16x4v __attribute__((ext_vector_type(4)));
typedef f16  f16x2  __attribute__((ext_vector_type(2)));
typedef float f32x4 __attribute__((ext_vector_type(4)));

#define MFMA_F16(a,b,c) __builtin_amdgcn_mfma_f32_16x16x32_f16((a),(b),(c),0,0,0)

#define NWIN 512
// Sb: [16 qrows][64 k][8 dwords + 16B pad] — each dword = f16x2 (same,diff)
// score pair for one head. Row stride 3088 B (≡16 mod 128 so b128 reads
// spread m&7 over 8 slots; 48 B k-slot spreads writes). NO XOR swizzle
// (R4/R5's XOR collided: rows not 128-aligned).
#define SB_QST 3088
#define SB_KST 48
// full-x staging: [64 tok][256 + 8 pad] f16 (528 B row)
#define BUFX_ST 264
// per-head QKV output scratch: Q/K swizzled [64][32] (4096 B), V transposed [32][72]
#define BUFO_HEAD 2304
#define VT_ST 72
// sm layout: bufX [0,33792) | bufO [33792,70656)
// attention reuse: Sb [0,49408) | sTbl [49408,65608)
// sTbl row stride = 9 floats: bank = (9*idx + h) mod 32 spreads the per-wave
// gather (h fixed per wave) over all banks; stride 8 pinned the wave to 4
// banks (~16-way serialization on 128 lookups/wave).
#define STBL_STRIDE 9
#define SM_BYTES 70656
#define STBL_OFF 49408

// load 8 consecutive fp32, round to f16x8
__device__ __forceinline__ f16x8 ld_f16x8(const float* __restrict__ p) {
  f32x4 a = *(const f32x4*)p;
  f32x4 b = *(const f32x4*)(p + 4);
  f16x8 r;
  r[0] = (f16)a[0]; r[1] = (f16)a[1]; r[2] = (f16)a[2]; r[3] = (f16)a[3];
  r[4] = (f16)b[0]; r[5] = (f16)b[1]; r[6] = (f16)b[2]; r[7] = (f16)b[3];
  return r;
}

// ---------------- prep: CPB MLP table + weight f32->f16 conversion ----------
__global__ __launch_bounds__(256) void prep_all(
    const float* __restrict__ w1a, const float* __restrict__ b1a,
    const float* __restrict__ w2a,
    const float* __restrict__ w1b, const float* __restrict__ b1b,
    const float* __restrict__ w2b,
    const float* __restrict__ qkvw1, const float* __restrict__ qkvw2,
    const float* __restrict__ pw1, const float* __restrict__ pw2,
    float* __restrict__ sg16,
    f16* __restrict__ wq1f, f16* __restrict__ wq2f,
    f16* __restrict__ pw1f, f16* __restrict__ pw2f) {
  const int b = blockIdx.x;
  if (b >= 450) {
    const int cb = b - 450;
    const float* src; f16* dst; int base;
    if (cb < 96)       { src = qkvw1; dst = wq1f; base = cb * 2048; }
    else if (cb < 192) { src = qkvw2; dst = wq2f; base = (cb - 96) * 2048; }
    else if (cb < 224) { src = pw1;   dst = pw1f; base = (cb - 192) * 2048; }
    else               { src = pw2;   dst = pw2f; base = (cb - 224) * 2048; }
    const int o = base + threadIdx.x * 8;
    *(f16x8*)(dst + o) = ld_f16x8(src + o);
    return;
  }
  const int view = b / 225;
  const int e    = b % 225;
  const float* __restrict__ w1 = view ? w1b : w1a;
  const float* __restrict__ b1 = view ? b1b : b1a;
  const float* __restrict__ w2 = view ? w2b : w2a;
  const int t = threadIdx.x;
  const int i = e / 15, j = e % 15;
  const float vi = 8.0f * (float)(i - 7) * (1.0f / 7.0f);
  const float vj = 8.0f * (float)(j - 7) * (1.0f / 7.0f);
  const float in0 = copysignf(log2f(fabsf(vi) + 1.0f) * (1.0f / 3.0f), vi);
  const float in1 = copysignf(log2f(fabsf(vj) + 1.0f) * (1.0f / 3.0f), vj);
  float acc[8] = {0.f,0.f,0.f,0.f,0.f,0.f,0.f,0.f};
#pragma unroll
  for (int uu = 0; uu < 2; ++uu) {
    const int u = t + uu * 256;
    float hv = fmaxf(w1[2*u] * in0 + w1[2*u+1] * in1 + b1[u], 0.0f);
#pragma unroll
    for (int hh = 0; hh < 8; ++hh) acc[hh] += w2[hh*512 + u] * hv;
  }
#pragma unroll
  for (int off = 32; off >= 1; off >>= 1)
#pragma unroll
    for (int hh = 0; hh < 8; ++hh) acc[hh] += __shfl_xor(acc[hh], off, 64);
  __shared__ float red[4][8];
  if ((t & 63) == 0) {
#pragma unroll
    for (int hh = 0; hh < 8; ++hh) red[t >> 6][hh] = acc[hh];
  }
  __syncthreads();
  if (t < 8) {
    float s = red[0][t] + red[1][t] + red[2][t] + red[3][t];
    sg16[(view * 225 + e) * 8 + t] = 16.0f / (1.0f + __expf(-s));
  }
}

// ---------------- fused: per-window (both views) QKV + attention + proj ------
// launch_bounds (512, 2): LDS caps at 2 blocks/CU; asking 4 (R2) forced
// VGPR=64 -> ~350 MB scratch spill. 2 -> 128 VGPR, no spill.
// NOTE (R10 lesson): arg2 behaves CUDA-style (min BLOCKS/CU): (512,2)->128
// VGPR, (512,4)->64, (1024,4)->64. Keep (512,2).
__global__ __launch_bounds__(512, 2) void fused_attn(
    const float* __restrict__ x1, const float* __restrict__ x2,
    const f16* __restrict__ qkvw1, const float* __restrict__ qb1, const float* __restrict__ vb1,
    const f16* __restrict__ qkvw2, const float* __restrict__ qb2, const float* __restrict__ vb2,
    const float* __restrict__ pcw1, const float* __restrict__ pcb1, const float* __restrict__ ls1,
    const float* __restrict__ pcw2, const float* __restrict__ pcb2, const float* __restrict__ ls2,
    const f16* __restrict__ pw1, const float* __restrict__ pb1,
    const f16* __restrict__ pw2, const float* __restrict__ pb2,
    const float* __restrict__ sg16,
    float* __restrict__ outp) {
  const int win = blockIdx.x;
  const int tid = threadIdx.x;
  const int lane = tid & 63, h = tid >> 6;
  const int quad = lane >> 4, m = lane & 15;

  __shared__ __align__(16) char sm[SM_BYTES];
  f16* bufX  = (f16*)sm;
  f16* bufO  = (f16*)(sm + 33792);
  char* Sbc  = sm;                    // Sb accessed via byte addresses
  f16* preB  = (f16*)sm;
  float* sTbl = (float*)(sm + STBL_OFF);

  const f32x4 z4 = {0.f, 0.f, 0.f, 0.f};
  f16x8 aqF[2][4], kfF[2][4], bvF[2][2][2];
  f16* oh = bufO + h * BUFO_HEAD;

  // ================= QKV GEMMs, both views =================
  for (int view = 0; view < 2; ++view) {
    const float* __restrict__ xv = (view ? x2 : x1) + (size_t)win * (64 * 256);
    const f16* __restrict__ W    = view ? qkvw2 : qkvw1;
    const float* __restrict__ qb = view ? qb2 : qb1;
    const float* __restrict__ vb = view ? vb2 : vb1;

    __syncthreads();   // bufX/bufO safe to overwrite (prev view's reads done)
    for (int i = tid; i < 2048; i += 512) {           // 64 rows x 32 chunks of 8
      const int row = i >> 5, c8 = i & 31;
      *(f16x8*)(bufX + row * BUFX_ST + c8 * 8) = ld_f16x8(xv + row * 256 + c8 * 8);
    }
    __syncthreads();   // bufX ready (stable for all 3 secs)

    for (int sec = 0; sec < 3; ++sec) {
      f32x4 acc0[4], acc1[4];
#pragma unroll
      for (int t = 0; t < 4; ++t) { acc0[t] = z4; acc1[t] = z4; }
      const f16* wb = W + (size_t)(sec * 256 + h * 32) * 256 + quad * 8;
      __builtin_amdgcn_s_setprio(1);
#pragma unroll 2
      for (int k8 = 0; k8 < 8; ++k8) {
        f16x8 a0 = *(const f16x8*)(wb + (size_t)m * 256 + k8 * 32);
        f16x8 a1 = *(const f16x8*)(wb + (size_t)(16 + m) * 256 + k8 * 32);
#pragma unroll
        for (int tt = 0; tt < 4; ++tt) {
          f16x8 bfr = *(const f16x8*)(bufX + (tt * 16 + m) * BUFX_ST + k8 * 32 + quad * 8);
          acc0[tt] = MFMA_F16(a0, bfr, acc0[tt]);
          acc1[tt] = MFMA_F16(a1, bfr, acc1[tt]);
        }
      }
      __builtin_amdgcn_s_setprio(0);
      // epilogue: bias, (l2norm q/k), write to own head's bufO region.
      float bs0[4], bs1[4];
#pragma unroll
      for (int r = 0; r < 4; ++r) {
        int c0 = h * 32 + quad * 4 + r;
        bs0[r] = (sec == 0) ? qb[c0] : (sec == 2 ? vb[c0] : 0.f);
        bs1[r] = (sec == 0) ? qb[c0 + 16] : (sec == 2 ? vb[c0 + 16] : 0.f);
      }
#pragma unroll
      for (int tt = 0; tt < 4; ++tt) {
        float v0[4], v1[4];
#pragma unroll
        for (int r = 0; r < 4; ++r) { v0[r] = acc0[tt][r] + bs0[r]; v1[r] = acc1[tt][r] + bs1[r]; }
        if (sec < 2) {
          float ss = 0.f;
#pragma unroll
          for (int r = 0; r < 4; ++r) ss += v0[r] * v0[r] + v1[r] * v1[r];
          ss += __shfl_xor(ss, 16, 64);
          ss += __shfl_xor(ss, 32, 64);
          float s = 1.0f / fmaxf(sqrtf(ss), 1e-12f);
#pragma unroll
          for (int r = 0; r < 4; ++r) { v0[r] *= s; v1[r] *= s; }
        }
        const int n = tt * 16 + m;
        if (sec < 2) {
          // Q/K: swizzled [tok][32ch] layout (bijective within 64B rows)
          f16x4v p0, p1;
#pragma unroll
          for (int r = 0; r < 4; ++r) { p0[r] = (f16)v0[r]; p1[r] = (f16)v1[r]; }
          char* ob = (char*)oh;
          const int sw = (n & 7) << 4;
          *(f16x4v*)(ob + ((n * 64 + quad * 8) ^ sw))      = p0;
          *(f16x4v*)(ob + ((n * 64 + 32 + quad * 8) ^ sw)) = p1;
        } else {
          // V: store transposed Vt[ch][tok] so fragment reads are vector loads
#pragma unroll
          for (int r = 0; r < 4; ++r) {
            oh[(quad * 4 + r) * VT_ST + n]      = (f16)v0[r];
            oh[(quad * 4 + 16 + r) * VT_ST + n] = (f16)v1[r];
          }
        }
      }
      // fragment extraction — own-head region only, no barrier needed
      if (sec == 0) {
#pragma unroll
        for (int rt = 0; rt < 4; ++rt) {
          const int n = rt * 16 + m;
          aqF[view][rt] = *(const f16x8*)((char*)oh + ((n * 64 + quad * 16) ^ ((n & 7) << 4)));
        }
      } else if (sec == 1) {
#pragma unroll
        for (int ct = 0; ct < 4; ++ct) {
          const int n = ct * 16 + m;
          kfF[view][ct] = *(const f16x8*)((char*)oh + ((n * 64 + quad * 16) ^ ((n & 7) << 4)));
        }
      } else {
#pragma unroll
        for (int nt = 0; nt < 2; ++nt)
#pragma unroll
          for (int kv = 0; kv < 2; ++kv)
            bvF[view][nt][kv] = *(const f16x8*)(oh + (nt * 16 + m) * VT_ST + kv * 32 + quad * 8);
      }
    }
  }
  __syncthreads();   // all fragments in regs; sm free for Sb/sTbl

  // load bias table once for BOTH views; store with row stride 9 (bank spread)
  for (int i = tid; i < 3600; i += 512)
    sTbl[(i >> 3) * STBL_STRIDE + (i & 7)] = sg16[i];

  // ================= attention + proj, both views =================
#pragma unroll
  for (int view = 0; view < 2; ++view) {
    const float* __restrict__ pcw = view ? pcw2 : pcw1;
    // fdot2 weight pairs matched to Sb's (same,diff) dword packing.
    f16x2 w0[4], w1[4];
#pragma unroll
    for (int c = 0; c < 4; ++c) {
      f16x2 a, b;
      a[0] = (f16)pcw[h * 16 + c];     a[1] = (f16)pcw[h * 16 + 8 + c];
      b[0] = (f16)pcw[h * 16 + 4 + c]; b[1] = (f16)pcw[h * 16 + 12 + c];
      w0[c] = a; w1[c] = b;
    }
    const float pcb_h = (view ? pcb2 : pcb1)[h];
    const float lsv = (view ? ls2 : ls1)[h];
    const float scale_h = __expf(fminf(lsv, 4.6051702f));
    const float pcbs = pcb_h * scale_h;
    const float* tblv = sTbl + view * (225 * STBL_STRIDE);

    f32x4 oacc[4][2];
#pragma unroll
    for (int rt = 0; rt < 4; ++rt) {
      f16x8 aq = aqF[view][rt];
      // Score MFMAs; pack (same,diff) per head into one dword -> ds_write_b32.
      __builtin_amdgcn_s_setprio(1);
#pragma unroll
      for (int ct = 0; ct < 4; ++ct) {
        const int kk = ct * 16 + m;
        const int wbase = kk * SB_KST + (h << 2);
        f32x4 Ss = MFMA_F16(aq, kfF[view][ct], z4);
        f32x4 Sd = MFMA_F16(aq, kfF[1 - view][ct], z4);
#pragma unroll
        for (int r = 0; r < 4; ++r) {
          f16x2 pr; pr[0] = (f16)Ss[r]; pr[1] = (f16)Sd[r];
          *(f16x2*)(Sbc + (quad * 4 + r) * SB_QST + wbase) = pr;
        }
      }
      __builtin_amdgcn_s_setprio(0);
      __syncthreads();   // B1: Sb complete (all heads' channels)

      // ---- logits: 16-ch mix via v_dot2_f32_f16; softmax; AV ----
      const int n = rt * 16 + m;
      const int nh_ = n >> 3, nw_ = n & 7;
      const int rbase = m * SB_QST;
      float logit[16];
#pragma unroll
      for (int j = 0; j < 16; ++j) {
        const int mm = (j < 8) ? (quad * 8 + j) : (32 + quad * 8 + (j - 8));
        const int b0 = rbase + mm * SB_KST;
        f16x8 s0 = *(const f16x8*)(Sbc + b0);        // heads 0-3: (s,d) pairs
        f16x8 s1 = *(const f16x8*)(Sbc + b0 + 16);   // heads 4-7
        const f16x2* s0p = (const f16x2*)&s0;
        const f16x2* s1p = (const f16x2*)&s1;
        float mix = 0.f;
#pragma unroll
        for (int c = 0; c < 4; ++c) {
          mix = __builtin_amdgcn_fdot2(s0p[c], w0[c], mix, false);
          mix = __builtin_amdgcn_fdot2(s1p[c], w1[c], mix, false);
        }
        const int idx = (nh_ - (mm >> 3) + 7) * 15 + (nw_ - (mm & 7) + 7);
        logit[j] = mix * scale_h + pcbs + tblv[idx * STBL_STRIDE + h];
      }
      float mx = -1e30f;
#pragma unroll
      for (int j = 0; j < 16; ++j) mx = fmaxf(mx, logit[j]);
      mx = fmaxf(mx, __shfl_xor(mx, 16, 64));
      mx = fmaxf(mx, __shfl_xor(mx, 32, 64));
      float p[16], sum = 0.f;
#pragma unroll
      for (int j = 0; j < 16; ++j) { p[j] = __expf(logit[j] - mx); sum += p[j]; }
      sum += __shfl_xor(sum, 16, 64);
      sum += __shfl_xor(sum, 32, 64);
      float inv = 1.0f / sum;
      f16x8 av0, av1;
#pragma unroll
      for (int j = 0; j < 8; ++j) { av0[j] = (f16)(p[j] * inv); av1[j] = (f16)(p[8 + j] * inv); }
      __builtin_amdgcn_s_setprio(1);
#pragma unroll
      for (int nt = 0; nt < 2; ++nt) {
        f32x4 z = z4;
        z = MFMA_F16(av0, bvF[view][nt][0], z);
        z = MFMA_F16(av1, bvF[view][nt][1], z);
        oacc[rt][nt] = z;
      }
      __builtin_amdgcn_s_setprio(0);
      __syncthreads();   // B2: Sb reads done before next rt overwrites
    }

    // ---- pre-projection activations -> preB ----
#pragma unroll
    for (int mt = 0; mt < 4; ++mt)
#pragma unroll
      for (int nt = 0; nt < 2; ++nt)
#pragma unroll
        for (int r = 0; r < 4; ++r)
          preB[(mt * 16 + quad * 4 + r) * 264 + h * 32 + nt * 16 + m] = (f16)oacc[mt][nt][r];
    __syncthreads();   // preB ready

    // ---- proj GEMM from preB (f16 weights) ----
    const f16* __restrict__ Wp = view ? pw2 : pw1;
    const float* __restrict__ pb = view ? pb2 : pb1;
    f32x4 pacc0[4], pacc1[4];
#pragma unroll
    for (int t = 0; t < 4; ++t) { pacc0[t] = z4; pacc1[t] = z4; }
    __builtin_amdgcn_s_setprio(1);
#pragma unroll 2
    for (int ks = 0; ks < 8; ++ks) {
      f16x8 pa0 = *(const f16x8*)(Wp + (size_t)(h * 32 + m) * 256 + ks * 32 + quad * 8);
      f16x8 pa1 = *(const f16x8*)(Wp + (size_t)(h * 32 + 16 + m) * 256 + ks * 32 + quad * 8);
#pragma unroll
      for (int tt = 0; tt < 4; ++tt) {
        f16x8 bfr = *(const f16x8*)(preB + (tt * 16 + m) * 264 + ks * 32 + quad * 8);
        pacc0[tt] = MFMA_F16(pa0, bfr, pacc0[tt]);
        pacc1[tt] = MFMA_F16(pa1, bfr, pacc1[tt]);
      }
    }
    __builtin_amdgcn_s_setprio(0);
    // ---- FP32 output store ----
    float* obase = outp + (size_t)(view * NWIN + win) * (64 * 256);
#pragma unroll
    for (int tt = 0; tt < 4; ++tt) {
      f32x4 p0, p1;
#pragma unroll
      for (int r = 0; r < 4; ++r) {
        p0[r] = pacc0[tt][r] + pb[h * 32 + quad * 4 + r];
        p1[r] = pacc1[tt][r] + pb[h * 32 + 16 + quad * 4 + r];
      }
      const int n = tt * 16 + m;
      *(f32x4*)(obase + n * 256 + h * 32 + quad * 4)      = p0;
      *(f32x4*)(obase + n * 256 + h * 32 + 16 + quad * 4) = p1;
    }
    __syncthreads();   // preB/Sb reads done before next view reuses sm
  }
}

extern "C" void kernel_launch(void* const* d_in, const int* in_sizes, int n_in,
                              void* d_out, int out_size, void* d_ws, size_t ws_size,
                              hipStream_t stream) {
  (void)in_sizes; (void)n_in; (void)out_size; (void)ws_size;
  const float* x1   = (const float*)d_in[0];
  const float* x2   = (const float*)d_in[1];
  const float* qkvw1= (const float*)d_in[2];
  const float* qb1  = (const float*)d_in[3];
  const float* vb1  = (const float*)d_in[4];
  const float* pw1  = (const float*)d_in[5];
  const float* pb1  = (const float*)d_in[6];
  const float* ls1  = (const float*)d_in[7];
  const float* cw11 = (const float*)d_in[8];
  const float* cb11 = (const float*)d_in[9];
  const float* cw12 = (const float*)d_in[10];
  const float* pcw1 = (const float*)d_in[11];
  const float* pcb1 = (const float*)d_in[12];
  const float* qkvw2= (const float*)d_in[13];
  const float* qb2  = (const float*)d_in[14];
  const float* vb2  = (const float*)d_in[15];
  const float* pw2  = (const float*)d_in[16];
  const float* pb2  = (const float*)d_in[17];
  const float* ls2  = (const float*)d_in[18];
  const float* cw21 = (const float*)d_in[19];
  const float* cb21 = (const float*)d_in[20];
  const float* cw22 = (const float*)d_in[21];
  const float* pcw2 = (const float*)d_in[22];
  const float* pcb2 = (const float*)d_in[23];

  // workspace: sg16 [2][225][8] f32 (14400 B) | qkvw1 f16 | qkvw2 f16 |
  // pw1 f16 | pw2 f16  -> ~1.04 MB
  float* SG16 = (float*)d_ws;
  f16* wq1f = (f16*)((char*)d_ws + 14400);
  f16* wq2f = wq1f + 196608;
  f16* pw1f = wq2f + 196608;
  f16* pw2f = pw1f + 65536;
  float* out = (float*)d_out;

  prep_all<<<706, 256, 0, stream>>>(cw11, cb11, cw12, cw21, cb21, cw22,
                                    qkvw1, qkvw2, pw1, pw2,
                                    SG16, wq1f, wq2f, pw1f, pw2f);
  fused_attn<<<NWIN, 512, 0, stream>>>(x1, x2,
      wq1f, qb1, vb1, wq2f, qb2, vb2,
      pcw1, pcb1, ls1, pcw2, pcb2, ls2,
      pw1f, pb1, pw2f, pb2, SG16, out);
}